// Round 7
// baseline (583.525 us; speedup 1.0000x reference)
//
#include <hip/hip_runtime.h>
#include <hip/hip_fp16.h>
#include <math.h>

#define NEG 0.2f
#define CBITS 7               // coarse bucket = dst >> 7 (128 nodes/bucket)
#define CNODES 128

// leaky-relu + exp via hardware exp: lrelu(v) = max(v, 0.2v); __expf -> mul+v_exp_f32
__device__ __forceinline__ float pexp(float v) { return __expf(fmaxf(v, NEG * v)); }
__device__ __forceinline__ float eluf(float x) { return x > 0.0f ? x : __expf(x) - 1.0f; }
__device__ __forceinline__ float h2f(ushort u) { return __half2float(__ushort_as_half(u)); }

// ---------------- K1: gemm1 + fused attn-coef epilogue (blocks [0,NBg)) ----------------
//                     + coarse histogram (blocks [NBg, NBg+NBc))
__global__ __launch_bounds__(256) void k_gemm_coarse(const float* __restrict__ x,
                                                     const float* __restrict__ W,
                                                     ushort* __restrict__ h1g,
                                                     const float* __restrict__ as1,
                                                     const float* __restrict__ ad1,
                                                     float* __restrict__ asrc1,
                                                     float* __restrict__ adst1,
                                                     const int* __restrict__ ei,
                                                     int* __restrict__ coarse_hist,
                                                     int N, int E, int NBg, int NBK) {
  __shared__ float xs[128 * 40];
  __shared__ float ws[32 * 68];
  const int tid = threadIdx.x;

  if ((int)blockIdx.x >= NBg) {
    // -------- coarse count branch: 16384 edges/block, LDS histogram --------
    int* lh = (int*)xs;
    for (int q = tid; q < NBK; q += 256) lh[q] = 0;
    __syncthreads();
    int e_base = ((int)blockIdx.x - NBg) * 16384;
#pragma unroll 4
    for (int u = 0; u < 16; ++u) {
      int e = e_base + u * 1024 + tid * 4;
      if (e + 3 < E) {
        int4 d4 = *(const int4*)&ei[E + e];
        atomicAdd(&lh[d4.x >> CBITS], 1);
        atomicAdd(&lh[d4.y >> CBITS], 1);
        atomicAdd(&lh[d4.z >> CBITS], 1);
        atomicAdd(&lh[d4.w >> CBITS], 1);
      } else {
        for (int v = 0; v < 4; ++v) {
          int ee = e + v;
          if (ee < E) atomicAdd(&lh[ei[E + ee] >> CBITS], 1);
        }
      }
    }
    __syncthreads();
    for (int q = tid; q < NBK; q += 256) {
      int c = lh[q];
      if (c > 0) atomicAdd(&coarse_hist[q], c);
    }
    return;
  }

  // -------- gemm branch --------
  const int n0 = blockIdx.x * 128;
  const int jg = tid & 15;
  const int ig = tid >> 4;
  const int j0 = jg * 4;

  float acc[8][4];
#pragma unroll
  for (int i = 0; i < 8; ++i)
#pragma unroll
    for (int c = 0; c < 4; ++c) acc[i][c] = 0.0f;

  for (int kc = 0; kc < 512; kc += 32) {
#pragma unroll
    for (int p = 0; p < 4; ++p) {
      int q = tid + p * 256;
      int r = q >> 3, c4 = q & 7;
      int n = n0 + r;
      if (n >= N) n = N - 1;
      float4 v = *(const float4*)&x[(size_t)n * 512 + kc + c4 * 4];
      *(float4*)&xs[r * 40 + c4 * 4] = v;
    }
#pragma unroll
    for (int p = 0; p < 2; ++p) {
      int q = tid + p * 256;
      int r = q >> 4, c4 = q & 15;
      float4 v = *(const float4*)&W[(size_t)(kc + r) * 64 + c4 * 4];
      *(float4*)&ws[r * 68 + c4 * 4] = v;
    }
    __syncthreads();

#pragma unroll
    for (int k = 0; k < 32; k += 4) {
      float4 wf[4];
#pragma unroll
      for (int kk = 0; kk < 4; ++kk) wf[kk] = *(const float4*)&ws[(k + kk) * 68 + j0];
#pragma unroll
      for (int i = 0; i < 8; ++i) {
        int r = ig + 16 * i;
        float4 xf = *(const float4*)&xs[r * 40 + k];
        float xv;
        xv = xf.x;
        acc[i][0] += xv * wf[0].x; acc[i][1] += xv * wf[0].y;
        acc[i][2] += xv * wf[0].z; acc[i][3] += xv * wf[0].w;
        xv = xf.y;
        acc[i][0] += xv * wf[1].x; acc[i][1] += xv * wf[1].y;
        acc[i][2] += xv * wf[1].z; acc[i][3] += xv * wf[1].w;
        xv = xf.z;
        acc[i][0] += xv * wf[2].x; acc[i][1] += xv * wf[2].y;
        acc[i][2] += xv * wf[2].z; acc[i][3] += xv * wf[2].w;
        xv = xf.w;
        acc[i][0] += xv * wf[3].x; acc[i][1] += xv * wf[3].y;
        acc[i][2] += xv * wf[3].z; acc[i][3] += xv * wf[3].w;
      }
    }
    __syncthreads();
  }

  // epilogue: fp16 h1 store + fused attention coefficients (fp32)
  float as_c[4], ad_c[4];
#pragma unroll
  for (int c = 0; c < 4; ++c) {
    as_c[c] = as1[j0 + c];
    ad_c[c] = ad1[j0 + c];
  }
  const int h = jg >> 1;  // the head covered by this lane pair
#pragma unroll
  for (int i = 0; i < 8; ++i) {
    int n = n0 + ig + 16 * i;
    float ps = acc[i][0] * as_c[0] + acc[i][1] * as_c[1] + acc[i][2] * as_c[2] +
               acc[i][3] * as_c[3];
    float pd = acc[i][0] * ad_c[0] + acc[i][1] * ad_c[1] + acc[i][2] * ad_c[2] +
               acc[i][3] * ad_c[3];
    ps += __shfl_xor(ps, 1, 64);
    pd += __shfl_xor(pd, 1, 64);
    if (n < N) {
      ushort4 u;
      u.x = __half_as_ushort(__float2half_rn(acc[i][0]));
      u.y = __half_as_ushort(__float2half_rn(acc[i][1]));
      u.z = __half_as_ushort(__float2half_rn(acc[i][2]));
      u.w = __half_as_ushort(__float2half_rn(acc[i][3]));
      *(ushort4*)&h1g[(size_t)n * 64 + j0] = u;
      if ((jg & 1) == 0) {
        asrc1[(size_t)n * 8 + h] = ps;
        adst1[(size_t)n * 8 + h] = pd;
      }
    }
  }
}

// ---------------- K2: scan coarse histogram (single block, NBK <= 1024) ----------------
__global__ __launch_bounds__(1024) void k_coarse_scan(const int* __restrict__ coarse_hist,
                                                      int* __restrict__ coarse_off,
                                                      int* __restrict__ cursor,
                                                      int NBK, int E) {
  __shared__ int s[1024];
  int t = threadIdx.x;
  int own = t < NBK ? coarse_hist[t] : 0;
  s[t] = own;
  __syncthreads();
  for (int o = 1; o < 1024; o <<= 1) {
    int add = t >= o ? s[t - o] : 0;
    __syncthreads();
    s[t] += add;
    __syncthreads();
  }
  if (t < NBK) {
    int excl = s[t] - own;
    coarse_off[t] = excl;
    cursor[t] = excl;
  }
  if (t == 0) coarse_off[NBK] = E;
}

// ---------------- K3: bucket scatter (LDS-rank aggregated) ----------------
__global__ __launch_bounds__(256) void k_bucket_scatter(const int* __restrict__ ei,
                                                        int* __restrict__ cursor,
                                                        int* __restrict__ bucketed,
                                                        int E, int NBK) {
  __shared__ int hist[1024];
  __shared__ int basev[1024];
  const int tid = threadIdx.x;
  for (int q = tid; q < NBK; q += 256) hist[q] = 0;
  __syncthreads();
  const int e0 = blockIdx.x * 4096;
  int b[16], r[16];
#pragma unroll
  for (int u = 0; u < 16; ++u) {
    int e = e0 + u * 256 + tid;
    if (e < E) {
      int d = ei[E + e];
      b[u] = d >> CBITS;
      r[u] = atomicAdd(&hist[b[u]], 1);
    } else {
      b[u] = -1;
    }
  }
  __syncthreads();
  for (int q = tid; q < NBK; q += 256) {
    int c = hist[q];
    basev[q] = c > 0 ? atomicAdd(&cursor[q], c) : 0;
  }
  __syncthreads();
#pragma unroll
  for (int u = 0; u < 16; ++u) {
    if (b[u] >= 0) {
      int e = e0 + u * 256 + tid;
      int srcv = ei[e];
      int d = ei[E + e];
      bucketed[basev[b[u]] + r[u]] = (srcv << CBITS) | (d & (CNODES - 1));
    }
  }
}

// ---------------- K4: per-bucket fine CSR build, 4-padded rows ----------------
// padded base of bucket bkt = coarse_off[bkt] + 4*CNODES*bkt; each node's row start
// is 4-aligned so agg kernels can read the neighbor list with aligned int4 loads.
__global__ __launch_bounds__(256) void k_fine_csr(const int* __restrict__ bucketed,
                                                  const int* __restrict__ coarse_off,
                                                  int* __restrict__ rowstart,
                                                  int* __restrict__ deg,
                                                  int* __restrict__ csr, int N) {
  __shared__ int h[CNODES];
  __shared__ int excl[CNODES];
  const int tid = threadIdx.x;
  const int bkt = blockIdx.x;
  const int base = coarse_off[bkt];
  const int cnt = coarse_off[bkt + 1] - base;
  const int base_p = base + 4 * CNODES * bkt;  // padded base

  if (tid < CNODES) h[tid] = 0;
  __syncthreads();
  for (int i = tid; i < cnt; i += 256) atomicAdd(&h[bucketed[base + i] & (CNODES - 1)], 1);
  __syncthreads();
  // scan padded counts (round each up to multiple of 4) with one wave
  if (tid < 64) {
    int a = h[2 * tid], c = h[2 * tid + 1];
    int pa = (a + 3) & ~3, pc = (c + 3) & ~3;
    int ps = pa + pc;
    int sv = ps;
    for (int o = 1; o < 64; o <<= 1) {
      int tv = __shfl_up(sv, o, 64);
      if (tid >= o) sv += tv;
    }
    int e0v = sv - ps;
    excl[2 * tid] = e0v;
    excl[2 * tid + 1] = e0v + pa;
  }
  __syncthreads();
  if (tid < CNODES) {
    int node = bkt * CNODES + tid;
    if (node < N) {
      rowstart[node] = base_p + excl[tid];
      deg[node] = h[tid];
    }
  }
  __syncthreads();
  if (tid < CNODES) h[tid] = 0;
  __syncthreads();
  for (int i = tid; i < cnt; i += 256) {
    int v = bucketed[base + i];
    int loc = v & (CNODES - 1);
    int r = atomicAdd(&h[loc], 1);
    csr[base_p + excl[loc] + r] = v >> CBITS;
  }
}

// ---------------- layer 1 aggregation: wave per dst node, fused softmax+bias+ELU ---------
__global__ __launch_bounds__(256) void agg1(const int* __restrict__ rowstart,
                                            const int* __restrict__ deg,
                                            const int* __restrict__ csr,
                                            const float* __restrict__ asrc,
                                            const float* __restrict__ adst,
                                            const ushort* __restrict__ h1g,
                                            const float* __restrict__ b1,
                                            float* __restrict__ act, int N) {
  int wid = (blockIdx.x * 256 + threadIdx.x) >> 6;
  if (wid >= N) return;
  const int lane = threadIdx.x & 63;
  const int h = lane >> 3;
  const int d = wid;
  const float ad = adst[d * 8 + h];
  const int rs = rowstart[d], n = deg[d];
  float acc = 0.0f, zs = 0.0f;
  for (int i = 0; i < n; i += 4) {
    const int4 s4 = *(const int4*)&csr[rs + i];
    const int rem = n - i;  // >= 1
    const int s0 = s4.x;
    const int s1 = rem > 1 ? s4.y : d;
    const int s2 = rem > 2 ? s4.z : d;
    const int s3 = rem > 3 ? s4.w : d;
    float a0 = asrc[s0 * 8 + h] + ad;
    float a1 = asrc[s1 * 8 + h] + ad;
    float a2 = asrc[s2 * 8 + h] + ad;
    float a3 = asrc[s3 * 8 + h] + ad;
    float x0 = h2f(h1g[s0 * 64 + lane]);
    float x1 = h2f(h1g[s1 * 64 + lane]);
    float x2 = h2f(h1g[s2 * 64 + lane]);
    float x3 = h2f(h1g[s3 * 64 + lane]);
    float p0 = pexp(a0);
    float p1 = rem > 1 ? pexp(a1) : 0.0f;
    float p2 = rem > 2 ? pexp(a2) : 0.0f;
    float p3 = rem > 3 ? pexp(a3) : 0.0f;
    acc += p0 * x0 + p1 * x1 + p2 * x2 + p3 * x3;
    zs += (p0 + p1) + (p2 + p3);
  }
  // self loop
  {
    float p = pexp(asrc[d * 8 + h] + ad);
    acc += p * h2f(h1g[d * 64 + lane]);
    zs += p;
  }
  act[(size_t)d * 64 + lane] = eluf(acc / (zs + 1e-16f) + b1[lane]);
}

// ---------------- layer2 node kernel: h2 = act @ W2 (fp16 out), attention coefficients ----
__global__ __launch_bounds__(256) void node_l2(const float* __restrict__ act,
                                               const float* __restrict__ W2,
                                               const float* __restrict__ as2,
                                               const float* __restrict__ ad2,
                                               ushort* __restrict__ h2g,
                                               float* __restrict__ asrc2,
                                               float* __restrict__ adst2, int N) {
  __shared__ float acts[64 * 68];
  __shared__ float w2[64 * 40];
  __shared__ float h2s[64 * 41];
  const int tid = threadIdx.x;
  const int n0 = blockIdx.x * 64;

  for (int q = tid; q < 64 * 40; q += 256) w2[q] = W2[q];

#pragma unroll
  for (int p = 0; p < 4; ++p) {
    int q = tid + p * 256;
    int r = q >> 4, c4 = q & 15;
    int n = n0 + r;
    if (n >= N) n = N - 1;
    float4 v = *(const float4*)&act[(size_t)n * 64 + c4 * 4];
    *(float4*)&acts[r * 68 + c4 * 4] = v;
  }
  __syncthreads();

  const int nl = tid >> 2;
  const int k0 = (tid & 3) * 10;
  float hv[10];
#pragma unroll
  for (int i = 0; i < 10; ++i) hv[i] = 0.0f;
  for (int j = 0; j < 64; ++j) {
    float a = acts[nl * 68 + j];
#pragma unroll
    for (int i = 0; i < 10; ++i) hv[i] += a * w2[j * 40 + k0 + i];
  }
  int n = n0 + nl;
  if (n < N) {
#pragma unroll
    for (int i = 0; i < 10; i += 2) {
      ushort2 u;
      u.x = __half_as_ushort(__float2half_rn(hv[i]));
      u.y = __half_as_ushort(__float2half_rn(hv[i + 1]));
      *(ushort2*)&h2g[(size_t)n * 40 + k0 + i] = u;
    }
  }
#pragma unroll
  for (int i = 0; i < 10; ++i) h2s[nl * 41 + k0 + i] = hv[i];
  __syncthreads();

  if (tid < 64) {
    int nn = n0 + tid;
    float s1 = 0.0f, s2 = 0.0f;
    for (int k = 0; k < 40; ++k) {
      float h = h2s[tid * 41 + k];
      s1 += h * as2[k];
      s2 += h * ad2[k];
    }
    if (nn < N) {
      asrc2[nn] = s1;
      adst2[nn] = s2;
    }
  }
}

// ---------------- layer 2 aggregation: wave per dst node ----------------
__global__ __launch_bounds__(256) void agg2(const int* __restrict__ rowstart,
                                            const int* __restrict__ deg,
                                            const int* __restrict__ csr,
                                            const float* __restrict__ asrc,
                                            const float* __restrict__ adst,
                                            const ushort* __restrict__ h2g,
                                            const float* __restrict__ b2,
                                            float* __restrict__ out, int N) {
  int wid = (blockIdx.x * 256 + threadIdx.x) >> 6;
  if (wid >= N) return;
  const int lane = threadIdx.x & 63;
  const int d = wid;
  const float ad = adst[d];
  const int rs = rowstart[d], n = deg[d];
  const bool act_lane = lane < 40;
  float acc = 0.0f, zs = 0.0f;
  for (int i = 0; i < n; i += 4) {
    const int4 s4 = *(const int4*)&csr[rs + i];
    const int rem = n - i;
    const int s0 = s4.x;
    const int s1 = rem > 1 ? s4.y : d;
    const int s2 = rem > 2 ? s4.z : d;
    const int s3 = rem > 3 ? s4.w : d;
    float a0 = asrc[s0] + ad;
    float a1 = asrc[s1] + ad;
    float a2 = asrc[s2] + ad;
    float a3 = asrc[s3] + ad;
    float x0 = act_lane ? h2f(h2g[s0 * 40 + lane]) : 0.0f;
    float x1 = act_lane ? h2f(h2g[s1 * 40 + lane]) : 0.0f;
    float x2 = act_lane ? h2f(h2g[s2 * 40 + lane]) : 0.0f;
    float x3 = act_lane ? h2f(h2g[s3 * 40 + lane]) : 0.0f;
    float p0 = pexp(a0);
    float p1 = rem > 1 ? pexp(a1) : 0.0f;
    float p2 = rem > 2 ? pexp(a2) : 0.0f;
    float p3 = rem > 3 ? pexp(a3) : 0.0f;
    acc += p0 * x0 + p1 * x1 + p2 * x2 + p3 * x3;
    zs += (p0 + p1) + (p2 + p3);
  }
  {
    float p = pexp(asrc[d] + ad);
    float xv = act_lane ? h2f(h2g[d * 40 + lane]) : 0.0f;
    acc += p * xv;
    zs += p;
  }
  if (act_lane) out[(size_t)d * 40 + lane] = acc / (zs + 1e-16f) + b2[lane];
}

extern "C" void kernel_launch(void* const* d_in, const int* in_sizes, int n_in,
                              void* d_out, int out_size, void* d_ws, size_t ws_size,
                              hipStream_t stream) {
  const float* x   = (const float*)d_in[0];
  const int*   ei  = (const int*)d_in[1];
  const float* W1  = (const float*)d_in[2];
  const float* as1 = (const float*)d_in[3];
  const float* ad1 = (const float*)d_in[4];
  const float* b1  = (const float*)d_in[5];
  const float* W2  = (const float*)d_in[6];
  const float* as2 = (const float*)d_in[7];
  const float* ad2 = (const float*)d_in[8];
  const float* b2  = (const float*)d_in[9];
  float* out = (float*)d_out;

  const int N = in_sizes[0] / 512;
  const int E = in_sizes[1] / 2;
  const int NBK = (N + CNODES - 1) / CNODES;

  float* ws = (float*)d_ws;
  size_t o = 0;
  float* act   = ws + o; o += (size_t)N * 64;
  float* asrc1 = ws + o; o += (size_t)N * 8;
  float* adst1 = ws + o; o += (size_t)N * 8;
  float* asrc2 = ws + o; o += (size_t)N;
  float* adst2 = ws + o; o += (size_t)N;
  ushort* h1g  = (ushort*)(ws + o); o += (size_t)N * 32;  // N*64 halves
  ushort* h2g  = (ushort*)(ws + o); o += (size_t)N * 20 + 16;  // N*40 halves
  int* deg         = (int*)(ws + o); o += (size_t)N;
  int* rowstart    = (int*)(ws + o); o += (size_t)N;
  int* coarse_hist = (int*)(ws + o); o += 1024;
  int* coarse_off  = (int*)(ws + o); o += 1056;
  int* cursor      = (int*)(ws + o); o += 1024;
  int* bucketed    = (int*)(ws + o); o += (size_t)E;
  int* csr         = (int*)(ws + o); o += (size_t)E + 4 * CNODES * (size_t)NBK + 16;

  hipMemsetAsync(coarse_hist, 0, 1024 * sizeof(int), stream);

  const int NBg = (N + 127) / 128;
  const int NBc = (E + 16383) / 16384;
  k_gemm_coarse<<<NBg + NBc, 256, 0, stream>>>(x, W1, h1g, as1, ad1, asrc1, adst1, ei,
                                               coarse_hist, N, E, NBg, NBK);

  k_coarse_scan<<<1, 1024, 0, stream>>>(coarse_hist, coarse_off, cursor, NBK, E);

  const int NB3 = (E + 4095) / 4096;
  k_bucket_scatter<<<NB3, 256, 0, stream>>>(ei, cursor, bucketed, E, NBK);

  k_fine_csr<<<NBK, 256, 0, stream>>>(bucketed, coarse_off, rowstart, deg, csr, N);

  agg1<<<(N * 64 + 255) / 256, 256, 0, stream>>>(rowstart, deg, csr, asrc1, adst1, h1g, b1,
                                                 act, N);

  node_l2<<<(N + 63) / 64, 256, 0, stream>>>(act, W2, as2, ad2, h2g, asrc2, adst2, N);

  agg2<<<(N * 64 + 255) / 256, 256, 0, stream>>>(rowstart, deg, csr, asrc2, adst2, h2g, b2,
                                                 out, N);
}

// Round 8
// 501.529 us; speedup vs baseline: 1.1635x; 1.1635x over previous
//
#include <hip/hip_runtime.h>
#include <hip/hip_fp16.h>
#include <math.h>

#define NEG 0.2f
#define CBITS 7               // coarse bucket = dst >> 7 (128 nodes/bucket)
#define CNODES 128

__device__ __forceinline__ float pexp(float v) { return __expf(fmaxf(v, NEG * v)); }
__device__ __forceinline__ float eluf(float x) { return x > 0.0f ? x : __expf(x) - 1.0f; }
__device__ __forceinline__ float h2f(ushort u) { return __half2float(__ushort_as_half(u)); }

// ---------------- K1: gemm1 + fused attn-coef epilogue (blocks [0,NBg)) ----------------
//                     + coarse histogram (blocks [NBg, NBg+NBc))
__global__ __launch_bounds__(256) void k_gemm_coarse(const float* __restrict__ x,
                                                     const float* __restrict__ W,
                                                     ushort* __restrict__ h1g,
                                                     const float* __restrict__ as1,
                                                     const float* __restrict__ ad1,
                                                     float* __restrict__ asrc1,
                                                     float* __restrict__ adst1,
                                                     const int* __restrict__ ei,
                                                     int* __restrict__ coarse_hist,
                                                     int N, int E, int NBg, int NBK) {
  __shared__ float xs[128 * 40];
  __shared__ float ws[32 * 68];
  const int tid = threadIdx.x;

  if ((int)blockIdx.x >= NBg) {
    int* lh = (int*)xs;
    for (int q = tid; q < NBK; q += 256) lh[q] = 0;
    __syncthreads();
    int e_base = ((int)blockIdx.x - NBg) * 16384;
#pragma unroll 4
    for (int u = 0; u < 16; ++u) {
      int e = e_base + u * 1024 + tid * 4;
      if (e + 3 < E) {
        int4 d4 = *(const int4*)&ei[E + e];
        atomicAdd(&lh[d4.x >> CBITS], 1);
        atomicAdd(&lh[d4.y >> CBITS], 1);
        atomicAdd(&lh[d4.z >> CBITS], 1);
        atomicAdd(&lh[d4.w >> CBITS], 1);
      } else {
        for (int v = 0; v < 4; ++v) {
          int ee = e + v;
          if (ee < E) atomicAdd(&lh[ei[E + ee] >> CBITS], 1);
        }
      }
    }
    __syncthreads();
    for (int q = tid; q < NBK; q += 256) {
      int c = lh[q];
      if (c > 0) atomicAdd(&coarse_hist[q], c);
    }
    return;
  }

  // -------- gemm branch --------
  const int n0 = blockIdx.x * 128;
  const int jg = tid & 15;
  const int ig = tid >> 4;
  const int j0 = jg * 4;

  float acc[8][4];
#pragma unroll
  for (int i = 0; i < 8; ++i)
#pragma unroll
    for (int c = 0; c < 4; ++c) acc[i][c] = 0.0f;

  for (int kc = 0; kc < 512; kc += 32) {
#pragma unroll
    for (int p = 0; p < 4; ++p) {
      int q = tid + p * 256;
      int r = q >> 3, c4 = q & 7;
      int n = n0 + r;
      if (n >= N) n = N - 1;
      float4 v = *(const float4*)&x[(size_t)n * 512 + kc + c4 * 4];
      *(float4*)&xs[r * 40 + c4 * 4] = v;
    }
#pragma unroll
    for (int p = 0; p < 2; ++p) {
      int q = tid + p * 256;
      int r = q >> 4, c4 = q & 15;
      float4 v = *(const float4*)&W[(size_t)(kc + r) * 64 + c4 * 4];
      *(float4*)&ws[r * 68 + c4 * 4] = v;
    }
    __syncthreads();

#pragma unroll
    for (int k = 0; k < 32; k += 4) {
      float4 wf[4];
#pragma unroll
      for (int kk = 0; kk < 4; ++kk) wf[kk] = *(const float4*)&ws[(k + kk) * 68 + j0];
#pragma unroll
      for (int i = 0; i < 8; ++i) {
        int r = ig + 16 * i;
        float4 xf = *(const float4*)&xs[r * 40 + k];
        float xv;
        xv = xf.x;
        acc[i][0] += xv * wf[0].x; acc[i][1] += xv * wf[0].y;
        acc[i][2] += xv * wf[0].z; acc[i][3] += xv * wf[0].w;
        xv = xf.y;
        acc[i][0] += xv * wf[1].x; acc[i][1] += xv * wf[1].y;
        acc[i][2] += xv * wf[1].z; acc[i][3] += xv * wf[1].w;
        xv = xf.z;
        acc[i][0] += xv * wf[2].x; acc[i][1] += xv * wf[2].y;
        acc[i][2] += xv * wf[2].z; acc[i][3] += xv * wf[2].w;
        xv = xf.w;
        acc[i][0] += xv * wf[3].x; acc[i][1] += xv * wf[3].y;
        acc[i][2] += xv * wf[3].z; acc[i][3] += xv * wf[3].w;
      }
    }
    __syncthreads();
  }

  float as_c[4], ad_c[4];
#pragma unroll
  for (int c = 0; c < 4; ++c) {
    as_c[c] = as1[j0 + c];
    ad_c[c] = ad1[j0 + c];
  }
  const int h = jg >> 1;
#pragma unroll
  for (int i = 0; i < 8; ++i) {
    int n = n0 + ig + 16 * i;
    float ps = acc[i][0] * as_c[0] + acc[i][1] * as_c[1] + acc[i][2] * as_c[2] +
               acc[i][3] * as_c[3];
    float pd = acc[i][0] * ad_c[0] + acc[i][1] * ad_c[1] + acc[i][2] * ad_c[2] +
               acc[i][3] * ad_c[3];
    ps += __shfl_xor(ps, 1, 64);
    pd += __shfl_xor(pd, 1, 64);
    if (n < N) {
      ushort4 u;
      u.x = __half_as_ushort(__float2half_rn(acc[i][0]));
      u.y = __half_as_ushort(__float2half_rn(acc[i][1]));
      u.z = __half_as_ushort(__float2half_rn(acc[i][2]));
      u.w = __half_as_ushort(__float2half_rn(acc[i][3]));
      *(ushort4*)&h1g[(size_t)n * 64 + j0] = u;
      if ((jg & 1) == 0) {
        asrc1[(size_t)n * 8 + h] = ps;
        adst1[(size_t)n * 8 + h] = pd;
      }
    }
  }
}

// ---------------- K2: scan coarse histogram + write sentinels ----------------
__global__ __launch_bounds__(1024) void k_coarse_scan(const int* __restrict__ coarse_hist,
                                                      int* __restrict__ coarse_off,
                                                      int* __restrict__ cursor,
                                                      float* __restrict__ asrc1,
                                                      float* __restrict__ asrc2,
                                                      int NBK, int E, int N) {
  __shared__ int s[1024];
  int t = threadIdx.x;
  int own = t < NBK ? coarse_hist[t] : 0;
  s[t] = own;
  __syncthreads();
  for (int o = 1; o < 1024; o <<= 1) {
    int add = t >= o ? s[t - o] : 0;
    __syncthreads();
    s[t] += add;
    __syncthreads();
  }
  if (t < NBK) {
    int excl = s[t] - own;
    coarse_off[t] = excl;
    cursor[t] = excl;
  }
  if (t == 0) coarse_off[NBK] = E;
  // sentinel attention values for pad node N: p = exp(-inf) = 0
  if (t < 8) asrc1[(size_t)N * 8 + t] = -1e30f;
  if (t == 8) asrc2[N] = -1e30f;
}

// ---------------- K3: bucket scatter (LDS-rank aggregated) ----------------
__global__ __launch_bounds__(256) void k_bucket_scatter(const int* __restrict__ ei,
                                                        int* __restrict__ cursor,
                                                        int* __restrict__ bucketed,
                                                        int E, int NBK) {
  __shared__ int hist[1024];
  __shared__ int basev[1024];
  const int tid = threadIdx.x;
  for (int q = tid; q < NBK; q += 256) hist[q] = 0;
  __syncthreads();
  const int e0 = blockIdx.x * 4096;
  int b[16], r[16];
#pragma unroll
  for (int u = 0; u < 16; ++u) {
    int e = e0 + u * 256 + tid;
    if (e < E) {
      int d = ei[E + e];
      b[u] = d >> CBITS;
      r[u] = atomicAdd(&hist[b[u]], 1);
    } else {
      b[u] = -1;
    }
  }
  __syncthreads();
  for (int q = tid; q < NBK; q += 256) {
    int c = hist[q];
    basev[q] = c > 0 ? atomicAdd(&cursor[q], c) : 0;
  }
  __syncthreads();
#pragma unroll
  for (int u = 0; u < 16; ++u) {
    if (b[u] >= 0) {
      int e = e0 + u * 256 + tid;
      int srcv = ei[e];
      int d = ei[E + e];
      bucketed[basev[b[u]] + r[u]] = (srcv << CBITS) | (d & (CNODES - 1));
    }
  }
}

// ---------------- K4: per-bucket fine CSR, rows padded to 8, pads = sentinel N ----------
__global__ __launch_bounds__(256) void k_fine_csr(const int* __restrict__ bucketed,
                                                  const int* __restrict__ coarse_off,
                                                  int* __restrict__ rowstart,
                                                  int* __restrict__ deg,
                                                  int* __restrict__ csr, int N) {
  __shared__ int h[CNODES];
  __shared__ int excl[CNODES];
  __shared__ int stot;
  const int tid = threadIdx.x;
  const int bkt = blockIdx.x;
  const int base = coarse_off[bkt];
  const int cnt = coarse_off[bkt + 1] - base;
  const int base_p = base + 8 * CNODES * bkt;  // padded base

  if (tid < CNODES) h[tid] = 0;
  __syncthreads();
  for (int i = tid; i < cnt; i += 256) atomicAdd(&h[bucketed[base + i] & (CNODES - 1)], 1);
  __syncthreads();
  // scan padded (round-to-8) counts with one wave
  if (tid < 64) {
    int a = h[2 * tid], c = h[2 * tid + 1];
    int pa = (a + 7) & ~7, pc = (c + 7) & ~7;
    int ps = pa + pc;
    int sv = ps;
    for (int o = 1; o < 64; o <<= 1) {
      int tv = __shfl_up(sv, o, 64);
      if (tid >= o) sv += tv;
    }
    int e0v = sv - ps;
    excl[2 * tid] = e0v;
    excl[2 * tid + 1] = e0v + pa;
    if (tid == 63) stot = sv;  // total padded slots this bucket
  }
  __syncthreads();
  if (tid < CNODES) {
    int node = bkt * CNODES + tid;
    if (node < N) {
      rowstart[node] = base_p + excl[tid];
      deg[node] = h[tid];
    }
  }
  // fill all padded slots with sentinel N, then scatter real values over them
  const int tot = stot;
  __syncthreads();
  for (int i = tid; i < tot; i += 256) csr[base_p + i] = N;
  if (tid < CNODES) h[tid] = 0;
  __syncthreads();
  for (int i = tid; i < cnt; i += 256) {
    int v = bucketed[base + i];
    int loc = v & (CNODES - 1);
    int r = atomicAdd(&h[loc], 1);
    csr[base_p + excl[loc] + r] = v >> CBITS;
  }
}

// ---------------- layer 1 aggregation: wave per dst, branch-free, p-dedup ----------------
__global__ __launch_bounds__(256) void agg1(const int* __restrict__ rowstart,
                                            const int* __restrict__ deg,
                                            const int* __restrict__ csr,
                                            const float* __restrict__ asrc,
                                            const float* __restrict__ adst,
                                            const ushort* __restrict__ h1g,
                                            const float* __restrict__ b1,
                                            float* __restrict__ act, int N) {
  int wid = (blockIdx.x * 256 + threadIdx.x) >> 6;
  if (wid >= N) return;
  const int lane = threadIdx.x & 63;
  const int hh = lane >> 3;     // head
  const int cl = lane & 7;      // assigned edge within chunk
  const int shbase = lane & 56; // head-group base lane
  const int d = wid;
  const float ad = adst[d * 8 + hh];
  const int rs = rowstart[d];
  const int n = deg[d];
  const int np = (n + 7) & ~7;
  float acc = 0.0f, zs = 0.0f;
  for (int i = 0; i < np; i += 8) {
    const int4 A = *(const int4*)&csr[rs + i];
    const int4 B = *(const int4*)&csr[rs + i + 4];
    // this lane computes p for edge cl (its head); pads have asrc=-1e30 -> p=0
    const int sl = csr[rs + i + cl];
    const float al = asrc[sl * 8 + hh] + ad;
    const float pl = __expf(fmaxf(al, NEG * al));
    int sarr[8] = {A.x, A.y, A.z, A.w, B.x, B.y, B.z, B.w};
#pragma unroll
    for (int j = 0; j < 8; ++j) {
      const float p = __shfl(pl, shbase + j, 64);
      const float xv = h2f(h1g[sarr[j] * 64 + lane]);
      acc = fmaf(p, xv, acc);
      zs += p;
    }
  }
  // self loop
  {
    const float a = asrc[d * 8 + hh] + ad;
    const float p = __expf(fmaxf(a, NEG * a));
    acc = fmaf(p, h2f(h1g[d * 64 + lane]), acc);
    zs += p;
  }
  act[(size_t)d * 64 + lane] = eluf(acc / (zs + 1e-16f) + b1[lane]);
}

// ---------------- layer2 node kernel: h2 = act @ W2 (fp16 out), attn coefficients --------
__global__ __launch_bounds__(256) void node_l2(const float* __restrict__ act,
                                               const float* __restrict__ W2,
                                               const float* __restrict__ as2,
                                               const float* __restrict__ ad2,
                                               ushort* __restrict__ h2g,
                                               float* __restrict__ asrc2,
                                               float* __restrict__ adst2, int N) {
  __shared__ float acts[64 * 68];
  __shared__ float w2[64 * 40];
  __shared__ float h2s[64 * 41];
  const int tid = threadIdx.x;
  const int n0 = blockIdx.x * 64;

  for (int q = tid; q < 64 * 40; q += 256) w2[q] = W2[q];

#pragma unroll
  for (int p = 0; p < 4; ++p) {
    int q = tid + p * 256;
    int r = q >> 4, c4 = q & 15;
    int n = n0 + r;
    if (n >= N) n = N - 1;
    float4 v = *(const float4*)&act[(size_t)n * 64 + c4 * 4];
    *(float4*)&acts[r * 68 + c4 * 4] = v;
  }
  __syncthreads();

  const int nl = tid >> 2;
  const int k0 = (tid & 3) * 10;
  float hv[10];
#pragma unroll
  for (int i = 0; i < 10; ++i) hv[i] = 0.0f;
  for (int j = 0; j < 64; ++j) {
    float a = acts[nl * 68 + j];
#pragma unroll
    for (int i = 0; i < 10; ++i) hv[i] += a * w2[j * 40 + k0 + i];
  }
  int n = n0 + nl;
  if (n < N) {
#pragma unroll
    for (int i = 0; i < 10; i += 2) {
      ushort2 u;
      u.x = __half_as_ushort(__float2half_rn(hv[i]));
      u.y = __half_as_ushort(__float2half_rn(hv[i + 1]));
      *(ushort2*)&h2g[(size_t)n * 40 + k0 + i] = u;
    }
  }
#pragma unroll
  for (int i = 0; i < 10; ++i) h2s[nl * 41 + k0 + i] = hv[i];
  __syncthreads();

  if (tid < 64) {
    int nn = n0 + tid;
    float s1 = 0.0f, s2 = 0.0f;
    for (int k = 0; k < 40; ++k) {
      float h = h2s[tid * 41 + k];
      s1 += h * as2[k];
      s2 += h * ad2[k];
    }
    if (nn < N) {
      asrc2[nn] = s1;
      adst2[nn] = s2;
    }
  }
}

// ---------------- layer 2 aggregation: wave per dst, branch-free, p-dedup ----------------
__global__ __launch_bounds__(256) void agg2(const int* __restrict__ rowstart,
                                            const int* __restrict__ deg,
                                            const int* __restrict__ csr,
                                            const float* __restrict__ asrc,
                                            const float* __restrict__ adst,
                                            const ushort* __restrict__ h2g,
                                            const float* __restrict__ b2,
                                            float* __restrict__ out, int N) {
  int wid = (blockIdx.x * 256 + threadIdx.x) >> 6;
  if (wid >= N) return;
  const int lane = threadIdx.x & 63;
  const int cl = lane & 7;
  const int d = wid;
  const float ad = adst[d];
  const int rs = rowstart[d];
  const int n = deg[d];
  const int np = (n + 7) & ~7;
  float acc = 0.0f, zs = 0.0f;
  for (int i = 0; i < np; i += 8) {
    const int4 A = *(const int4*)&csr[rs + i];
    const int4 B = *(const int4*)&csr[rs + i + 4];
    const int sl = csr[rs + i + cl];
    const float al = asrc[sl] + ad;
    const float pl = __expf(fmaxf(al, NEG * al));
    int sarr[8] = {A.x, A.y, A.z, A.w, B.x, B.y, B.z, B.w};
#pragma unroll
    for (int j = 0; j < 8; ++j) {
      const float p = __shfl(pl, j, 64);  // lane j computed edge j
      const float xv = h2f(h2g[sarr[j] * 40 + lane]);  // lanes>=40 read pad, masked at store
      acc = fmaf(p, xv, acc);
      zs += p;
    }
  }
  {
    const float a = asrc[d] + ad;
    const float p = __expf(fmaxf(a, NEG * a));
    acc = fmaf(p, h2f(h2g[d * 40 + lane]), acc);
    zs += p;
  }
  if (lane < 40) out[(size_t)d * 40 + lane] = acc / (zs + 1e-16f) + b2[lane];
}

extern "C" void kernel_launch(void* const* d_in, const int* in_sizes, int n_in,
                              void* d_out, int out_size, void* d_ws, size_t ws_size,
                              hipStream_t stream) {
  const float* x   = (const float*)d_in[0];
  const int*   ei  = (const int*)d_in[1];
  const float* W1  = (const float*)d_in[2];
  const float* as1 = (const float*)d_in[3];
  const float* ad1 = (const float*)d_in[4];
  const float* b1  = (const float*)d_in[5];
  const float* W2  = (const float*)d_in[6];
  const float* as2 = (const float*)d_in[7];
  const float* ad2 = (const float*)d_in[8];
  const float* b2  = (const float*)d_in[9];
  float* out = (float*)d_out;

  const int N = in_sizes[0] / 512;
  const int E = in_sizes[1] / 2;
  const int NBK = (N + CNODES - 1) / CNODES;

  float* ws = (float*)d_ws;
  size_t o = 0;
  float* act   = ws + o; o += (size_t)N * 64;
  float* asrc1 = ws + o; o += (size_t)N * 8 + 8;     // +sentinel row N
  float* adst1 = ws + o; o += (size_t)N * 8;
  float* asrc2 = ws + o; o += (size_t)N + 1;         // +sentinel
  float* adst2 = ws + o; o += (size_t)N;
  ushort* h1g  = (ushort*)(ws + o); o += (size_t)N * 32 + 64;  // N*64+64 halves (pad row)
  ushort* h2g  = (ushort*)(ws + o); o += (size_t)N * 20 + 64;  // N*40+64 halves (pad row)
  int* deg         = (int*)(ws + o); o += (size_t)N;
  int* rowstart    = (int*)(ws + o); o += (size_t)N;
  int* coarse_hist = (int*)(ws + o); o += 1024;
  int* coarse_off  = (int*)(ws + o); o += 1056;
  int* cursor      = (int*)(ws + o); o += 1024;
  int* bucketed    = (int*)(ws + o); o += (size_t)E;
  int* csr         = (int*)(ws + o); o += (size_t)E + 8 * CNODES * (size_t)NBK + 64;

  hipMemsetAsync(coarse_hist, 0, 1024 * sizeof(int), stream);
  // zero the sentinel h-rows (pad edges gather from row N; p=0 so value must be finite)
  hipMemsetAsync(h1g + (size_t)N * 64, 0, 128 * sizeof(ushort), stream);
  hipMemsetAsync(h2g + (size_t)N * 40, 0, 64 * sizeof(ushort), stream);

  const int NBg = (N + 127) / 128;
  const int NBc = (E + 16383) / 16384;
  k_gemm_coarse<<<NBg + NBc, 256, 0, stream>>>(x, W1, h1g, as1, ad1, asrc1, adst1, ei,
                                               coarse_hist, N, E, NBg, NBK);

  k_coarse_scan<<<1, 1024, 0, stream>>>(coarse_hist, coarse_off, cursor, asrc1, asrc2,
                                        NBK, E, N);

  const int NB3 = (E + 4095) / 4096;
  k_bucket_scatter<<<NB3, 256, 0, stream>>>(ei, cursor, bucketed, E, NBK);

  k_fine_csr<<<NBK, 256, 0, stream>>>(bucketed, coarse_off, rowstart, deg, csr, N);

  agg1<<<(N * 64 + 255) / 256, 256, 0, stream>>>(rowstart, deg, csr, asrc1, adst1, h1g, b1,
                                                 act, N);

  node_l2<<<(N + 63) / 64, 256, 0, stream>>>(act, W2, as2, ad2, h2g, asrc2, adst2, N);

  agg2<<<(N * 64 + 255) / 256, 256, 0, stream>>>(rowstart, deg, csr, asrc2, adst2, h2g, b2,
                                                 out, N);
}

// Round 9
// 425.249 us; speedup vs baseline: 1.3722x; 1.1794x over previous
//
#include <hip/hip_runtime.h>
#include <hip/hip_fp16.h>
#include <math.h>

#define NEG 0.2f
#define CBITS 7               // coarse bucket = dst >> 7 (128 nodes/bucket)
#define CNODES 128

__device__ __forceinline__ float pexp(float v) { return __expf(fmaxf(v, NEG * v)); }
__device__ __forceinline__ float eluf(float x) { return x > 0.0f ? x : __expf(x) - 1.0f; }
__device__ __forceinline__ float h2f(ushort u) { return __half2float(__ushort_as_half(u)); }

// ---------------- K0: coarse histogram (standalone, runs before everything) ----------------
__global__ __launch_bounds__(256) void k_hist(const int* __restrict__ ei,
                                              int* __restrict__ coarse_hist,
                                              int E, int NBK) {
  __shared__ int lh[1024];
  const int tid = threadIdx.x;
  for (int q = tid; q < NBK; q += 256) lh[q] = 0;
  __syncthreads();
  int e_base = (int)blockIdx.x * 16384;
#pragma unroll 4
  for (int u = 0; u < 16; ++u) {
    int e = e_base + u * 1024 + tid * 4;
    if (e + 3 < E) {
      int4 d4 = *(const int4*)&ei[E + e];
      atomicAdd(&lh[d4.x >> CBITS], 1);
      atomicAdd(&lh[d4.y >> CBITS], 1);
      atomicAdd(&lh[d4.z >> CBITS], 1);
      atomicAdd(&lh[d4.w >> CBITS], 1);
    } else {
      for (int v = 0; v < 4; ++v) {
        int ee = e + v;
        if (ee < E) atomicAdd(&lh[ei[E + ee] >> CBITS], 1);
      }
    }
  }
  __syncthreads();
  for (int q = tid; q < NBK; q += 256) {
    int c = lh[q];
    if (c > 0) atomicAdd(&coarse_hist[q], c);
  }
}

// ---------------- K2: scan coarse histogram + write sentinels ----------------
__global__ __launch_bounds__(1024) void k_coarse_scan(const int* __restrict__ coarse_hist,
                                                      int* __restrict__ coarse_off,
                                                      int* __restrict__ cursor,
                                                      float* __restrict__ asrc1,
                                                      float* __restrict__ asrc2,
                                                      int NBK, int E, int N) {
  __shared__ int s[1024];
  int t = threadIdx.x;
  int own = t < NBK ? coarse_hist[t] : 0;
  s[t] = own;
  __syncthreads();
  for (int o = 1; o < 1024; o <<= 1) {
    int add = t >= o ? s[t - o] : 0;
    __syncthreads();
    s[t] += add;
    __syncthreads();
  }
  if (t < NBK) {
    int excl = s[t] - own;
    coarse_off[t] = excl;
    cursor[t] = excl;
  }
  if (t == 0) coarse_off[NBK] = E;
  // sentinel attention values for pad node N: p = exp(-inf) = 0
  if (t < 8) asrc1[(size_t)N * 8 + t] = -1e30f;
  if (t == 8) asrc2[N] = -1e30f;
}

// ---------------- K1: gemm1 (+fp16 h1 + fused attn coefs) blocks [0,NBg)  ----------------
//                     ∥ bucket scatter blocks [NBg, NBg+NB3)
__global__ __launch_bounds__(256) void k_gemm_scatter(const float* __restrict__ x,
                                                      const float* __restrict__ W,
                                                      ushort* __restrict__ h1g,
                                                      const float* __restrict__ as1,
                                                      const float* __restrict__ ad1,
                                                      float* __restrict__ asrc1,
                                                      float* __restrict__ adst1,
                                                      const int* __restrict__ ei,
                                                      int* __restrict__ cursor,
                                                      int* __restrict__ bucketed,
                                                      int N, int E, int NBg, int NBK) {
  __shared__ float xs[128 * 40];
  __shared__ float ws[32 * 68];
  const int tid = threadIdx.x;

  if ((int)blockIdx.x >= NBg) {
    // -------- bucket scatter branch (LDS-rank aggregated), LDS aliases xs --------
    int* hist = (int*)xs;
    int* basev = ((int*)xs) + 1024;
    for (int q = tid; q < NBK; q += 256) hist[q] = 0;
    __syncthreads();
    const int e0 = ((int)blockIdx.x - NBg) * 4096;
    int b[16], r[16];
#pragma unroll
    for (int u = 0; u < 16; ++u) {
      int e = e0 + u * 256 + tid;
      if (e < E) {
        int d = ei[E + e];
        b[u] = d >> CBITS;
        r[u] = atomicAdd(&hist[b[u]], 1);
      } else {
        b[u] = -1;
      }
    }
    __syncthreads();
    for (int q = tid; q < NBK; q += 256) {
      int c = hist[q];
      basev[q] = c > 0 ? atomicAdd(&cursor[q], c) : 0;
    }
    __syncthreads();
#pragma unroll
    for (int u = 0; u < 16; ++u) {
      if (b[u] >= 0) {
        int e = e0 + u * 256 + tid;
        int srcv = ei[e];
        int d = ei[E + e];
        bucketed[basev[b[u]] + r[u]] = (srcv << CBITS) | (d & (CNODES - 1));
      }
    }
    return;
  }

  // -------- gemm branch --------
  const int n0 = blockIdx.x * 128;
  const int jg = tid & 15;
  const int ig = tid >> 4;
  const int j0 = jg * 4;

  float acc[8][4];
#pragma unroll
  for (int i = 0; i < 8; ++i)
#pragma unroll
    for (int c = 0; c < 4; ++c) acc[i][c] = 0.0f;

  for (int kc = 0; kc < 512; kc += 32) {
#pragma unroll
    for (int p = 0; p < 4; ++p) {
      int q = tid + p * 256;
      int r = q >> 3, c4 = q & 7;
      int n = n0 + r;
      if (n >= N) n = N - 1;
      float4 v = *(const float4*)&x[(size_t)n * 512 + kc + c4 * 4];
      *(float4*)&xs[r * 40 + c4 * 4] = v;
    }
#pragma unroll
    for (int p = 0; p < 2; ++p) {
      int q = tid + p * 256;
      int r = q >> 4, c4 = q & 15;
      float4 v = *(const float4*)&W[(size_t)(kc + r) * 64 + c4 * 4];
      *(float4*)&ws[r * 68 + c4 * 4] = v;
    }
    __syncthreads();

#pragma unroll
    for (int k = 0; k < 32; k += 4) {
      float4 wf[4];
#pragma unroll
      for (int kk = 0; kk < 4; ++kk) wf[kk] = *(const float4*)&ws[(k + kk) * 68 + j0];
#pragma unroll
      for (int i = 0; i < 8; ++i) {
        int r = ig + 16 * i;
        float4 xf = *(const float4*)&xs[r * 40 + k];
        float xv;
        xv = xf.x;
        acc[i][0] += xv * wf[0].x; acc[i][1] += xv * wf[0].y;
        acc[i][2] += xv * wf[0].z; acc[i][3] += xv * wf[0].w;
        xv = xf.y;
        acc[i][0] += xv * wf[1].x; acc[i][1] += xv * wf[1].y;
        acc[i][2] += xv * wf[1].z; acc[i][3] += xv * wf[1].w;
        xv = xf.z;
        acc[i][0] += xv * wf[2].x; acc[i][1] += xv * wf[2].y;
        acc[i][2] += xv * wf[2].z; acc[i][3] += xv * wf[2].w;
        xv = xf.w;
        acc[i][0] += xv * wf[3].x; acc[i][1] += xv * wf[3].y;
        acc[i][2] += xv * wf[3].z; acc[i][3] += xv * wf[3].w;
      }
    }
    __syncthreads();
  }

  float as_c[4], ad_c[4];
#pragma unroll
  for (int c = 0; c < 4; ++c) {
    as_c[c] = as1[j0 + c];
    ad_c[c] = ad1[j0 + c];
  }
  const int h = jg >> 1;
#pragma unroll
  for (int i = 0; i < 8; ++i) {
    int n = n0 + ig + 16 * i;
    float ps = acc[i][0] * as_c[0] + acc[i][1] * as_c[1] + acc[i][2] * as_c[2] +
               acc[i][3] * as_c[3];
    float pd = acc[i][0] * ad_c[0] + acc[i][1] * ad_c[1] + acc[i][2] * ad_c[2] +
               acc[i][3] * ad_c[3];
    ps += __shfl_xor(ps, 1, 64);
    pd += __shfl_xor(pd, 1, 64);
    if (n < N) {
      ushort4 u;
      u.x = __half_as_ushort(__float2half_rn(acc[i][0]));
      u.y = __half_as_ushort(__float2half_rn(acc[i][1]));
      u.z = __half_as_ushort(__float2half_rn(acc[i][2]));
      u.w = __half_as_ushort(__float2half_rn(acc[i][3]));
      *(ushort4*)&h1g[(size_t)n * 64 + j0] = u;
      if ((jg & 1) == 0) {
        asrc1[(size_t)n * 8 + h] = ps;
        adst1[(size_t)n * 8 + h] = pd;
      }
    }
  }
}

// ---------------- K4: per-bucket fine CSR, rows padded to 8, pads = sentinel N ----------
__global__ __launch_bounds__(256) void k_fine_csr(const int* __restrict__ bucketed,
                                                  const int* __restrict__ coarse_off,
                                                  int* __restrict__ rowstart,
                                                  int* __restrict__ deg,
                                                  int* __restrict__ csr, int N) {
  __shared__ int h[CNODES];
  __shared__ int excl[CNODES];
  __shared__ int stot;
  const int tid = threadIdx.x;
  const int bkt = blockIdx.x;
  const int base = coarse_off[bkt];
  const int cnt = coarse_off[bkt + 1] - base;
  const int base_p = base + 8 * CNODES * bkt;  // padded base

  if (tid < CNODES) h[tid] = 0;
  __syncthreads();
  for (int i = tid; i < cnt; i += 256) atomicAdd(&h[bucketed[base + i] & (CNODES - 1)], 1);
  __syncthreads();
  if (tid < 64) {
    int a = h[2 * tid], c = h[2 * tid + 1];
    int pa = (a + 7) & ~7, pc = (c + 7) & ~7;
    int ps = pa + pc;
    int sv = ps;
    for (int o = 1; o < 64; o <<= 1) {
      int tv = __shfl_up(sv, o, 64);
      if (tid >= o) sv += tv;
    }
    int e0v = sv - ps;
    excl[2 * tid] = e0v;
    excl[2 * tid + 1] = e0v + pa;
    if (tid == 63) stot = sv;
  }
  __syncthreads();
  if (tid < CNODES) {
    int node = bkt * CNODES + tid;
    if (node < N) {
      rowstart[node] = base_p + excl[tid];
      deg[node] = h[tid];
    }
  }
  const int tot = stot;
  __syncthreads();
  for (int i = tid; i < tot; i += 256) csr[base_p + i] = N;
  if (tid < CNODES) h[tid] = 0;
  __syncthreads();
  for (int i = tid; i < cnt; i += 256) {
    int v = bucketed[base + i];
    int loc = v & (CNODES - 1);
    int r = atomicAdd(&h[loc], 1);
    csr[base_p + excl[loc] + r] = v >> CBITS;
  }
}

// ---------------- layer 1 aggregation: wave per dst, branch-free, p-dedup ----------------
__global__ __launch_bounds__(256) void agg1(const int* __restrict__ rowstart,
                                            const int* __restrict__ deg,
                                            const int* __restrict__ csr,
                                            const float* __restrict__ asrc,
                                            const float* __restrict__ adst,
                                            const ushort* __restrict__ h1g,
                                            const float* __restrict__ b1,
                                            float* __restrict__ act, int N) {
  int wid = (blockIdx.x * 256 + threadIdx.x) >> 6;
  if (wid >= N) return;
  const int lane = threadIdx.x & 63;
  const int hh = lane >> 3;
  const int cl = lane & 7;
  const int shbase = lane & 56;
  const int d = wid;
  const float ad = adst[d * 8 + hh];
  const int rs = rowstart[d];
  const int n = deg[d];
  const int np = (n + 7) & ~7;
  float acc = 0.0f, zs = 0.0f;
  for (int i = 0; i < np; i += 8) {
    const int4 A = *(const int4*)&csr[rs + i];
    const int4 B = *(const int4*)&csr[rs + i + 4];
    const int sl = csr[rs + i + cl];
    const float al = asrc[sl * 8 + hh] + ad;
    const float pl = __expf(fmaxf(al, NEG * al));
    int sarr[8] = {A.x, A.y, A.z, A.w, B.x, B.y, B.z, B.w};
#pragma unroll
    for (int j = 0; j < 8; ++j) {
      const float p = __shfl(pl, shbase + j, 64);
      const float xv = h2f(h1g[sarr[j] * 64 + lane]);
      acc = fmaf(p, xv, acc);
      zs += p;
    }
  }
  {
    const float a = asrc[d * 8 + hh] + ad;
    const float p = __expf(fmaxf(a, NEG * a));
    acc = fmaf(p, h2f(h1g[d * 64 + lane]), acc);
    zs += p;
  }
  act[(size_t)d * 64 + lane] = eluf(acc / (zs + 1e-16f) + b1[lane]);
}

// ---------------- layer2 node kernel: h2 = act @ W2 (fp16 out), attn coefficients --------
__global__ __launch_bounds__(256) void node_l2(const float* __restrict__ act,
                                               const float* __restrict__ W2,
                                               const float* __restrict__ as2,
                                               const float* __restrict__ ad2,
                                               ushort* __restrict__ h2g,
                                               float* __restrict__ asrc2,
                                               float* __restrict__ adst2, int N) {
  __shared__ float acts[64 * 68];
  __shared__ float w2[64 * 40];
  __shared__ float h2s[64 * 41];
  const int tid = threadIdx.x;
  const int n0 = blockIdx.x * 64;

  for (int q = tid; q < 64 * 40; q += 256) w2[q] = W2[q];

#pragma unroll
  for (int p = 0; p < 4; ++p) {
    int q = tid + p * 256;
    int r = q >> 4, c4 = q & 15;
    int n = n0 + r;
    if (n >= N) n = N - 1;
    float4 v = *(const float4*)&act[(size_t)n * 64 + c4 * 4];
    *(float4*)&acts[r * 68 + c4 * 4] = v;
  }
  __syncthreads();

  const int nl = tid >> 2;
  const int k0 = (tid & 3) * 10;
  float hv[10];
#pragma unroll
  for (int i = 0; i < 10; ++i) hv[i] = 0.0f;
  for (int j = 0; j < 64; ++j) {
    float a = acts[nl * 68 + j];
#pragma unroll
    for (int i = 0; i < 10; ++i) hv[i] += a * w2[j * 40 + k0 + i];
  }
  int n = n0 + nl;
  if (n < N) {
#pragma unroll
    for (int i = 0; i < 10; i += 2) {
      ushort2 u;
      u.x = __half_as_ushort(__float2half_rn(hv[i]));
      u.y = __half_as_ushort(__float2half_rn(hv[i + 1]));
      *(ushort2*)&h2g[(size_t)n * 40 + k0 + i] = u;
    }
  }
#pragma unroll
  for (int i = 0; i < 10; ++i) h2s[nl * 41 + k0 + i] = hv[i];
  __syncthreads();

  if (tid < 64) {
    int nn = n0 + tid;
    float s1 = 0.0f, s2 = 0.0f;
    for (int k = 0; k < 40; ++k) {
      float h = h2s[tid * 41 + k];
      s1 += h * as2[k];
      s2 += h * ad2[k];
    }
    if (nn < N) {
      asrc2[nn] = s1;
      adst2[nn] = s2;
    }
  }
}

// ---------------- layer 2 aggregation: wave per dst, branch-free, p-dedup ----------------
__global__ __launch_bounds__(256) void agg2(const int* __restrict__ rowstart,
                                            const int* __restrict__ deg,
                                            const int* __restrict__ csr,
                                            const float* __restrict__ asrc,
                                            const float* __restrict__ adst,
                                            const ushort* __restrict__ h2g,
                                            const float* __restrict__ b2,
                                            float* __restrict__ out, int N) {
  int wid = (blockIdx.x * 256 + threadIdx.x) >> 6;
  if (wid >= N) return;
  const int lane = threadIdx.x & 63;
  const int cl = lane & 7;
  const int d = wid;
  const float ad = adst[d];
  const int rs = rowstart[d];
  const int n = deg[d];
  const int np = (n + 7) & ~7;
  float acc = 0.0f, zs = 0.0f;
  for (int i = 0; i < np; i += 8) {
    const int4 A = *(const int4*)&csr[rs + i];
    const int4 B = *(const int4*)&csr[rs + i + 4];
    const int sl = csr[rs + i + cl];
    const float al = asrc[sl] + ad;
    const float pl = __expf(fmaxf(al, NEG * al));
    int sarr[8] = {A.x, A.y, A.z, A.w, B.x, B.y, B.z, B.w};
#pragma unroll
    for (int j = 0; j < 8; ++j) {
      const float p = __shfl(pl, j, 64);
      const float xv = h2f(h2g[sarr[j] * 40 + lane]);
      acc = fmaf(p, xv, acc);
      zs += p;
    }
  }
  {
    const float a = asrc[d] + ad;
    const float p = __expf(fmaxf(a, NEG * a));
    acc = fmaf(p, h2f(h2g[d * 40 + lane]), acc);
    zs += p;
  }
  if (lane < 40) out[(size_t)d * 40 + lane] = acc / (zs + 1e-16f) + b2[lane];
}

extern "C" void kernel_launch(void* const* d_in, const int* in_sizes, int n_in,
                              void* d_out, int out_size, void* d_ws, size_t ws_size,
                              hipStream_t stream) {
  const float* x   = (const float*)d_in[0];
  const int*   ei  = (const int*)d_in[1];
  const float* W1  = (const float*)d_in[2];
  const float* as1 = (const float*)d_in[3];
  const float* ad1 = (const float*)d_in[4];
  const float* b1  = (const float*)d_in[5];
  const float* W2  = (const float*)d_in[6];
  const float* as2 = (const float*)d_in[7];
  const float* ad2 = (const float*)d_in[8];
  const float* b2  = (const float*)d_in[9];
  float* out = (float*)d_out;

  const int N = in_sizes[0] / 512;
  const int E = in_sizes[1] / 2;
  const int NBK = (N + CNODES - 1) / CNODES;

  float* ws = (float*)d_ws;
  size_t o = 0;
  float* act   = ws + o; o += (size_t)N * 64;
  float* asrc1 = ws + o; o += (size_t)N * 8 + 8;     // +sentinel row N
  float* adst1 = ws + o; o += (size_t)N * 8;
  float* asrc2 = ws + o; o += (size_t)N + 1;         // +sentinel
  float* adst2 = ws + o; o += (size_t)N;
  ushort* h1g  = (ushort*)(ws + o); o += (size_t)N * 32 + 64;  // N*64+64 halves (pad row)
  ushort* h2g  = (ushort*)(ws + o); o += (size_t)N * 20 + 64;  // N*40+64 halves (pad row)
  int* deg         = (int*)(ws + o); o += (size_t)N;
  int* rowstart    = (int*)(ws + o); o += (size_t)N;
  int* coarse_hist = (int*)(ws + o); o += 1024;
  int* coarse_off  = (int*)(ws + o); o += 1056;
  int* cursor      = (int*)(ws + o); o += 1024;
  int* bucketed    = (int*)(ws + o); o += (size_t)E;
  int* csr         = (int*)(ws + o); o += (size_t)E + 8 * CNODES * (size_t)NBK + 64;

  hipMemsetAsync(coarse_hist, 0, 1024 * sizeof(int), stream);
  hipMemsetAsync(h1g + (size_t)N * 64, 0, 128 * sizeof(ushort), stream);
  hipMemsetAsync(h2g + (size_t)N * 40, 0, 64 * sizeof(ushort), stream);

  const int NBg = (N + 127) / 128;
  const int NBc = (E + 16383) / 16384;
  const int NB3 = (E + 4095) / 4096;

  // CSR-metadata pipeline front-end (cheap): histogram + scan
  k_hist<<<NBc, 256, 0, stream>>>(ei, coarse_hist, E, NBK);
  k_coarse_scan<<<1, 1024, 0, stream>>>(coarse_hist, coarse_off, cursor, asrc1, asrc2,
                                        NBK, E, N);

  // gemm ∥ bucket-scatter (independent work overlapped in one dispatch)
  k_gemm_scatter<<<NBg + NB3, 256, 0, stream>>>(x, W1, h1g, as1, ad1, asrc1, adst1, ei,
                                                cursor, bucketed, N, E, NBg, NBK);

  k_fine_csr<<<NBK, 256, 0, stream>>>(bucketed, coarse_off, rowstart, deg, csr, N);

  agg1<<<(N * 64 + 255) / 256, 256, 0, stream>>>(rowstart, deg, csr, asrc1, adst1, h1g, b1,
                                                 act, N);

  node_l2<<<(N + 63) / 64, 256, 0, stream>>>(act, W2, as2, ad2, h2g, asrc2, adst2, N);

  agg2<<<(N * 64 + 255) / 256, 256, 0, stream>>>(rowstart, deg, csr, asrc2, adst2, h2g, b2,
                                                 out, N);
}